// Round 14
// baseline (435.088 us; speedup 1.0000x reference)
//
#include <hip/hip_runtime.h>
#include <math.h>

#define N_NODES 50000
#define E_EDGES 800000
#define E_PAD (E_EDGES + 4 * N_NODES)   // padded srclist capacity (pad to x4)
#define FDIM_IN 128
#define HID_1 32
#define HEADS_1 8
#define H1DIM 256
#define NUM_WALKS 512
#define WALK_LEN 64
#define WINDOW 5
#define NEG_S 10
#define TEMP 0.07f
#define INV_TEMP (1.0f / 0.07f)
#define NEG_SLOPE 0.2f
#define LOG2E 1.44269504f

#define SCAN_BLOCKS ((N_NODES + 255) / 256)   // 196

typedef unsigned int uint;
typedef unsigned short ushort;
typedef long long i64_t;
typedef __attribute__((ext_vector_type(8))) short bf16x8;
typedef __attribute__((ext_vector_type(4))) float f32x4;
typedef __attribute__((ext_vector_type(2))) float vf2;

__device__ __forceinline__ float leaky(float v) {
    return fmaxf(v, v * NEG_SLOPE);
}

__device__ __forceinline__ float bfl(uint u) { return __uint_as_float(u << 16); }
__device__ __forceinline__ float bfh(uint u) { return __uint_as_float(u & 0xffff0000u); }

__device__ __forceinline__ ushort f2bf(float x) {
    uint u = __float_as_uint(x);
    u = u + 0x7fffu + ((u >> 16) & 1u);   // round-to-nearest-even
    return (ushort)(u >> 16);
}

// pack 4 f32 -> 4 fp8(e4m3) in one uint (HW converter; self-consistent with decode)
__device__ __forceinline__ uint pk4fp8(float a, float b, float c, float d) {
    int u = __builtin_amdgcn_cvt_pk_fp8_f32(a, b, 0, false);
    u = __builtin_amdgcn_cvt_pk_fp8_f32(c, d, u, true);
    return (uint)u;
}

// ---------------- CSR build (rows padded to multiples of 4 with sentinel) ----------------

__global__ void deg_kernel(const int* __restrict__ ei, int* __restrict__ deg) {
    int e = blockIdx.x * blockDim.x + threadIdx.x;
    if (e < E_EDGES) atomicAdd(&deg[ei[E_EDGES + e]], 1);
}

__global__ __launch_bounds__(256) void scan_a(const int* __restrict__ deg,
                                              int* __restrict__ excl,
                                              int* __restrict__ bsum) {
    __shared__ int s[256];
    int t = threadIdx.x;
    int i = blockIdx.x * 256 + t;
    int d = (i < N_NODES) ? deg[i] : 0;
    int v = (d + 3) & ~3;                // padded degree
    s[t] = v;
    __syncthreads();
    for (int off = 1; off < 256; off <<= 1) {
        int tmp = (t >= off) ? s[t - off] : 0;
        __syncthreads();
        s[t] += tmp;
        __syncthreads();
    }
    if (i < N_NODES) excl[i] = s[t] - v;
    if (t == 255) bsum[blockIdx.x] = s[255];
}

__global__ __launch_bounds__(256) void scan_b(int* __restrict__ bsum) {
    __shared__ int s[256];
    int t = threadIdx.x;
    int v = (t < SCAN_BLOCKS) ? bsum[t] : 0;
    s[t] = v;
    __syncthreads();
    for (int off = 1; off < 256; off <<= 1) {
        int tmp = (t >= off) ? s[t - off] : 0;
        __syncthreads();
        s[t] += tmp;
        __syncthreads();
    }
    if (t < SCAN_BLOCKS) bsum[t] = s[t] - v;   // exclusive
}

__global__ void scan_c2(const int* __restrict__ deg,
                        int* __restrict__ excl, const int* __restrict__ bsum,
                        int* __restrict__ row_start) {
    int i = blockIdx.x * blockDim.x + threadIdx.x;
    if (i < N_NODES) {
        int rs = excl[i] + bsum[i >> 8];
        row_start[i] = rs;
        if (i == N_NODES - 1) row_start[N_NODES] = rs + ((deg[i] + 3) & ~3);
    }
}

__global__ void fill_sent_kernel(int* __restrict__ p, int n) {
    int i = blockIdx.x * blockDim.x + threadIdx.x;
    if (i < n) p[i] = N_NODES;           // sentinel node id
}

__global__ void sent_al_kernel(float* __restrict__ als1, float* __restrict__ als2) {
    int t = threadIdx.x;
    if (t < HEADS_1) als1[N_NODES * HEADS_1 + t] = -1e30f;
    if (t == HEADS_1) als2[N_NODES] = -1e30f;
}

__global__ void bucket_kernel(const int* __restrict__ ei,
                              const int* __restrict__ row_start,
                              int* __restrict__ cursor,
                              int* __restrict__ srclist) {
    int e = blockIdx.x * blockDim.x + threadIdx.x;
    if (e >= E_EDGES) return;
    int dst = ei[E_EDGES + e];
    int pos = atomicAdd(&cursor[dst], 1);
    srclist[row_start[dst] + pos] = ei[e];
}

// ---------------- dtype conversion ----------------

__global__ void f32_to_bf16_kernel(const float* __restrict__ src, uint* __restrict__ dst, int n4) {
    int i = blockIdx.x * blockDim.x + threadIdx.x;
    if (i >= n4) return;
    float4 v = ((const float4*)src)[i];
    uint2 p;
    p.x = (uint)f2bf(v.x) | ((uint)f2bf(v.y) << 16);
    p.y = (uint)f2bf(v.z) | ((uint)f2bf(v.w) << 16);
    ((uint2*)dst)[i] = p;
}

// W[K][256] fp32 -> Wt[256][K] bf16
__global__ void wtrans_kernel(const float* __restrict__ W, ushort* __restrict__ Wt, int K) {
    int tid = blockIdx.x * blockDim.x + threadIdx.x;
    if (tid >= 256 * K) return;
    int k = tid >> 8, n = tid & 255;
    Wt[n * K + k] = f2bf(W[k * 256 + n]);
}

// ---- MFMA GEMM + fused attention-logit epilogue ----
// Y8[M][256] (fp8) = A[M][K] * W[K][256]; als/ald[n][h] = dot(row, a_src/a_dst) * log2e
template<int K, int H>
__global__ __launch_bounds__(256) void mfma_gemm(
        const ushort* __restrict__ A,    // [M][K] bf16
        const ushort* __restrict__ Wt,   // [256][K] bf16 (transposed)
        uint* __restrict__ Y8,           // [M][256] fp8, 64 uints/row
        const float* __restrict__ a_src, // [H*hid] = [256]
        const float* __restrict__ a_dst,
        float* __restrict__ als, float* __restrict__ ald) {
    constexpr int KP = K + 8;
    constexpr int K8 = K / 8;
    __shared__ ushort As[16 * KP];
    __shared__ float Cs[16][260];
    __shared__ float sals[16][17], sald[16][17];
    const int m0 = blockIdx.x * 16;
    const int t = threadIdx.x;
    const uint4* Ag = (const uint4*)(A + (size_t)m0 * K);
    uint4* As4 = (uint4*)As;
    for (int i = t; i < 16 * K8; i += 256) {
        int r = i / K8, c8 = i % K8;
        As4[r * (K8 + 1) + c8] = Ag[i];
    }
    __syncthreads();
    const int wv = t >> 6, lane = t & 63;
    const int n0 = wv * 64;
    const int mrow = lane & 15, q = lane >> 4;
    f32x4 acc[4];
#pragma unroll
    for (int i = 0; i < 4; i++) acc[i] = (f32x4){0.f, 0.f, 0.f, 0.f};
    const ushort* arow = As + mrow * KP + q * 8;
#pragma unroll
    for (int k0 = 0; k0 < K; k0 += 32) {
        bf16x8 a = *(const bf16x8*)(arow + k0);
#pragma unroll
        for (int i = 0; i < 4; i++) {
            bf16x8 b = *(const bf16x8*)(Wt + (size_t)(n0 + i * 16 + mrow) * K + k0 + q * 8);
            acc[i] = __builtin_amdgcn_mfma_f32_16x16x32_bf16(a, b, acc[i], 0, 0, 0);
        }
    }
#pragma unroll
    for (int i = 0; i < 4; i++)
#pragma unroll
        for (int r = 0; r < 4; r++)
            Cs[q * 4 + r][n0 + i * 16 + mrow] = acc[i][r];
    __syncthreads();
    // fp8 pack: thread t packs row t>>4, cols (t&15)*16..+15
    {
        const int row = t >> 4, c0 = (t & 15) * 16;
        const float* cp = &Cs[row][c0];
        uint4 o;
        o.x = pk4fp8(cp[0],  cp[1],  cp[2],  cp[3]);
        o.y = pk4fp8(cp[4],  cp[5],  cp[6],  cp[7]);
        o.z = pk4fp8(cp[8],  cp[9],  cp[10], cp[11]);
        o.w = pk4fp8(cp[12], cp[13], cp[14], cp[15]);
        ((uint4*)(Y8 + (size_t)(m0 + row) * 64))[t & 15] = o;
    }
    // attention-logit partials: thread t = (row, 16-col segment)
    {
        const int row = t >> 4, seg = t & 15;
        const float* cr = &Cs[row][seg * 16];
        const float* asr = a_src + seg * 16;
        const float* adr = a_dst + seg * 16;
        float ps = 0.f, pd = 0.f;
#pragma unroll
        for (int c = 0; c < 16; c++) {
            float v = cr[c];
            ps += v * asr[c];
            pd += v * adr[c];
        }
        sals[row][seg] = ps; sald[row][seg] = pd;
    }
    __syncthreads();
    if (t < 16 * H) {
        constexpr int SPH = 16 / H;          // col-segments per head
        const int row = t / H, h = t - row * H;
        float s = 0.f, d = 0.f;
#pragma unroll
        for (int sg = 0; sg < SPH; sg++) {
            s += sals[row][h * SPH + sg];
            d += sald[row][h * SPH + sg];
        }
        als[(m0 + row) * H + h] = s * LOG2E;
        ald[(m0 + row) * H + h] = d * LOG2E;
    }
}

#define UN 4

// layer-1 gather: scalar wid, padded rows (no clamps), exp2 logits, 32-bit offsets
__global__ __launch_bounds__(256) void gat_gather1(
        const int* __restrict__ row_start, const int* __restrict__ srclist,
        const float* __restrict__ als, const float* __restrict__ ald,
        const uint* __restrict__ xw8,                    // fp8 rows, 64 uints/row
        const float* __restrict__ bias,
        ushort* __restrict__ emb1b) {                    // [N][256] bf16
    const int wid = __builtin_amdgcn_readfirstlane(blockIdx.x * 4 + (threadIdx.x >> 6));
    const uint lane = threadIdx.x & 63;
    const uint h = lane >> 3;
    const float ald_n = ald[wid * HEADS_1 + h];
    const int beg = row_start[wid], end = row_start[wid + 1];

    float ex0 = __builtin_amdgcn_exp2f(leaky(als[wid * HEADS_1 + h] + ald_n));
    uint u = xw8[((uint)wid << 6) + lane];
    vf2 lo = __builtin_amdgcn_cvt_pk_f32_fp8((int)u, false);
    vf2 hi = __builtin_amdgcn_cvt_pk_f32_fp8((int)u, true);
    float den = ex0;
    float a0 = ex0 * lo[0], a1 = ex0 * lo[1];
    float a2 = ex0 * hi[0], a3 = ex0 * hi[1];

    for (int i = beg; i < end; i += UN) {
        uint ss[UN]; uint rr[UN]; float ee[UN];
#pragma unroll
        for (int j = 0; j < UN; j++) ss[j] = (uint)srclist[i + j];
#pragma unroll
        for (int j = 0; j < UN; j++) rr[j] = xw8[(ss[j] << 6) + lane];
#pragma unroll
        for (int j = 0; j < UN; j++) ee[j] = als[ss[j] * HEADS_1 + h];
#pragma unroll
        for (int j = 0; j < UN; j++) {
            float ex = __builtin_amdgcn_exp2f(leaky(ee[j] + ald_n));   // sentinel -> 0
            vf2 l2 = __builtin_amdgcn_cvt_pk_f32_fp8((int)rr[j], false);
            vf2 h2 = __builtin_amdgcn_cvt_pk_f32_fp8((int)rr[j], true);
            den += ex;
            a0 += ex * l2[0]; a1 += ex * l2[1];
            a2 += ex * h2[0]; a3 += ex * h2[1];
        }
    }
    float inv = 1.f / den;
    float4 bv = ((const float4*)bias)[lane];
    float4 r;
    r.x = a0 * inv + bv.x; r.y = a1 * inv + bv.y;
    r.z = a2 * inv + bv.z; r.w = a3 * inv + bv.w;
    r.x = r.x > 0.f ? r.x : __expf(r.x) - 1.f;
    r.y = r.y > 0.f ? r.y : __expf(r.y) - 1.f;
    r.z = r.z > 0.f ? r.z : __expf(r.z) - 1.f;
    r.w = r.w > 0.f ? r.w : __expf(r.w) - 1.f;
    uint2 p;
    p.x = (uint)f2bf(r.x) | ((uint)f2bf(r.y) << 16);
    p.y = (uint)f2bf(r.z) | ((uint)f2bf(r.w) << 16);
    ((uint2*)emb1b)[((uint)wid << 6) + lane] = p;
}

// layer-2 gather fused with normalize + fp8 pack of embn
__global__ __launch_bounds__(256) void gat_gather2(
        const int* __restrict__ row_start, const int* __restrict__ srclist,
        const float* __restrict__ als, const float* __restrict__ ald,
        const uint* __restrict__ xw8,                    // fp8 rows, 64 uints/row
        const float* __restrict__ bias,
        const ushort* __restrict__ emb1b,                // [N][256] bf16
        uint* __restrict__ embn8) {                      // [N][512] fp8, 128 uints/row
    const int wid = __builtin_amdgcn_readfirstlane(blockIdx.x * 4 + (threadIdx.x >> 6));
    const uint lane = threadIdx.x & 63;
    const float ald_n = ald[wid];
    const int beg = row_start[wid], end = row_start[wid + 1];

    float ex0 = __builtin_amdgcn_exp2f(leaky(als[wid] + ald_n));
    uint u = xw8[((uint)wid << 6) + lane];
    vf2 lo = __builtin_amdgcn_cvt_pk_f32_fp8((int)u, false);
    vf2 hi = __builtin_amdgcn_cvt_pk_f32_fp8((int)u, true);
    float den = ex0;
    float a0 = ex0 * lo[0], a1 = ex0 * lo[1];
    float a2 = ex0 * hi[0], a3 = ex0 * hi[1];

    for (int i = beg; i < end; i += UN) {
        uint ss[UN]; uint rr[UN]; float ee[UN];
#pragma unroll
        for (int j = 0; j < UN; j++) ss[j] = (uint)srclist[i + j];
#pragma unroll
        for (int j = 0; j < UN; j++) rr[j] = xw8[(ss[j] << 6) + lane];
#pragma unroll
        for (int j = 0; j < UN; j++) ee[j] = als[ss[j]];
#pragma unroll
        for (int j = 0; j < UN; j++) {
            float ex = __builtin_amdgcn_exp2f(leaky(ee[j] + ald_n));   // sentinel -> 0
            vf2 l2 = __builtin_amdgcn_cvt_pk_f32_fp8((int)rr[j], false);
            vf2 h2 = __builtin_amdgcn_cvt_pk_f32_fp8((int)rr[j], true);
            den += ex;
            a0 += ex * l2[0]; a1 += ex * l2[1];
            a2 += ex * h2[0]; a3 += ex * h2[1];
        }
    }
    float inv = 1.f / den;
    float4 bv = ((const float4*)bias)[lane];
    float4 e2;
    e2.x = a0 * inv + bv.x; e2.y = a1 * inv + bv.y;
    e2.z = a2 * inv + bv.z; e2.w = a3 * inv + bv.w;
    uint2 u1 = ((const uint2*)emb1b)[((uint)wid << 6) + lane];
    float4 e1;
    e1.x = bfl(u1.x); e1.y = bfh(u1.x); e1.z = bfl(u1.y); e1.w = bfh(u1.y);

    float ssum = e1.x * e1.x + e1.y * e1.y + e1.z * e1.z + e1.w * e1.w
               + e2.x * e2.x + e2.y * e2.y + e2.z * e2.z + e2.w * e2.w;
#pragma unroll
    for (int o = 32; o > 0; o >>= 1) ssum += __shfl_xor(ssum, o, 64);
    float innv = 1.f / fmaxf(sqrtf(ssum), 1e-8f);

    uint p1 = pk4fp8(e1.x * innv, e1.y * innv, e1.z * innv, e1.w * innv);
    uint p2 = pk4fp8(e2.x * innv, e2.y * innv, e2.z * innv, e2.w * innv);
    embn8[((uint)wid << 7) + lane] = p1;        // dims 0..255   (emb1 part)
    embn8[((uint)wid << 7) + 64 + lane] = p2;   // dims 256..511 (emb2 part)
}

// ---------------- MFMA contrastive loss (fp8) ----------------

#define ANCH 16                         // anchors per block (walk segment)
#define MAXROWS (ANCH + 2 * WINDOW)     // 26 LDS rows max
#define ROWU 130                        // 520 B row stride (2 banks mod 32, conflict-free)

// one block per 16-anchor segment, 768 threads = 12 waves, one tile-job per wave.
__global__ __launch_bounds__(768) void loss_mfma_kernel(
        const uint* __restrict__ embn8,    // [N][512] fp8, 128 uints/row
        const int* __restrict__ walks, const int* __restrict__ negs,
        float* __restrict__ out) {
    __shared__ __align__(16) uint srows8[MAXROWS * ROWU];   // 13.5 KB
    __shared__ int wids[MAXROWS];
    __shared__ int snid[160];
    __shared__ float possum[16];
    __shared__ float negsum[16];
    const int blk = blockIdx.x;
    const int b = blk >> 2;                  // walk
    const int l0 = (blk & 3) * ANCH;         // first anchor of segment
    const int base = (l0 - WINDOW) > 0 ? (l0 - WINDOW) : 0;
    const int hi = (l0 + ANCH - 1 + WINDOW) < (WALK_LEN - 1) ? (l0 + ANCH - 1 + WINDOW) : (WALK_LEN - 1);
    const int cnt = hi - base + 1;           // 21..26
    const int t = threadIdx.x;
    const int w = __builtin_amdgcn_readfirstlane(t >> 6);   // 0..11 = this wave's job
    const int lane = t & 63;
    if (t < cnt) wids[t] = walks[b * WALK_LEN + base + t];
    if (t >= 64 && t < 64 + 160) snid[t - 64] = negs[(b * WALK_LEN + l0) * NEG_S + (t - 64)];
    if (t >= 224 && t < 240) { possum[t - 224] = 0.f; negsum[t - 224] = 0.f; }
    __syncthreads();
    for (int r = w; r < cnt; r += 12)
        ((uint2*)(srows8 + r * ROWU))[lane] = ((const uint2*)(embn8 + ((uint)wids[r] << 7)))[lane];
    __syncthreads();

    const int mrow = lane & 15, q = lane >> 4;
    const int arow = (l0 - base) + mrow;     // LDS row of anchor #mrow
    const char* embc = (const char*)embn8;   // byte rows, stride 512
    const char* ap = (const char*)(srows8 + arow * ROWU) + q * 8;

    const int job = w;
    f32x4 acc0 = {0.f, 0.f, 0.f, 0.f};
    f32x4 acc1 = {0.f, 0.f, 0.f, 0.f};
    if (job < 10) {
        // ---- neg tile: cands c = 16*job .. +15, col = mrow ----
        const int c = job * 16 + mrow;
        const int node = snid[c];
        const char* bp = embc + (((uint)node << 9) + (uint)(q * 8));
#pragma unroll
        for (int k0 = 0; k0 < 256; k0 += 32) {
            i64_t a0 = *(const i64_t*)(ap + k0);
            i64_t b0 = *(const i64_t*)(bp + k0);
            acc0 = __builtin_amdgcn_mfma_f32_16x16x32_fp8_fp8(a0, b0, acc0, 0, 0, 0);
            i64_t a1 = *(const i64_t*)(ap + k0 + 256);
            i64_t b1 = *(const i64_t*)(bp + k0 + 256);
            acc1 = __builtin_amdgcn_mfma_f32_16x16x32_fp8_fp8(a1, b1, acc1, 0, 0, 0);
        }
        const int owner = c / 10;
#pragma unroll
        for (int reg = 0; reg < 4; reg++) {
            const int a_local = q * 4 + reg;
            float e = 0.f;
            if (owner == a_local) {
                const int l_a = l0 + a_local;
                bool msk = false;
#pragma unroll
                for (int dj = -WINDOW; dj <= WINDOW; dj++) {
                    if (dj == 0) continue;
                    int p = l_a + dj;
                    if (p >= 0 && p < WALK_LEN && wids[p - base] == node) msk = true;
                }
                if (!msk) e = __expf((acc0[reg] + acc1[reg]) * INV_TEMP);
            }
#pragma unroll
            for (int o = 1; o < 16; o <<= 1) e += __shfl_xor(e, o, 64);
            if (mrow == 0 && e != 0.f) atomicAdd(&negsum[a_local], e);
        }
    } else {
        // ---- pos tile: LDS rows r = 16*(job-10) .. +15 ----
        const int r = (job - 10) * 16 + mrow;
        const int rc = r < (cnt - 1) ? r : (cnt - 1);
        const char* bp = (const char*)(srows8 + rc * ROWU) + q * 8;
#pragma unroll
        for (int k0 = 0; k0 < 256; k0 += 32) {
            i64_t a0 = *(const i64_t*)(ap + k0);
            i64_t b0 = *(const i64_t*)(bp + k0);
            acc0 = __builtin_amdgcn_mfma_f32_16x16x32_fp8_fp8(a0, b0, acc0, 0, 0, 0);
            i64_t a1 = *(const i64_t*)(ap + k0 + 256);
            i64_t b1 = *(const i64_t*)(bp + k0 + 256);
            acc1 = __builtin_amdgcn_mfma_f32_16x16x32_fp8_fp8(a1, b1, acc1, 0, 0, 0);
        }
        const int pg = base + r;                 // walk position of this row
#pragma unroll
        for (int reg = 0; reg < 4; reg++) {
            const int a_local = q * 4 + reg;
            const int l_a = l0 + a_local;
            const int d = pg - l_a;
            bool use = (r < cnt) && (d != 0) && (d >= -WINDOW) && (d <= WINDOW);
            float e = use ? __expf((acc0[reg] + acc1[reg]) * INV_TEMP) : 0.f;
#pragma unroll
            for (int o = 1; o < 16; o <<= 1) e += __shfl_xor(e, o, 64);
            if (mrow == 0 && e != 0.f) atomicAdd(&possum[a_local], e);
        }
    }
    __syncthreads();
    if (t < 16) {
        float term = logf(1.f + negsum[t] / possum[t]);   // possum > 0 always
#pragma unroll
        for (int o = 8; o > 0; o >>= 1) term += __shfl_xor(term, o, 64);
        if (t == 0) atomicAdd(out, term);
    }
}

extern "C" void kernel_launch(void* const* d_in, const int* in_sizes, int n_in,
                              void* d_out, int out_size, void* d_ws, size_t ws_size,
                              hipStream_t stream) {
    const float* x      = (const float*)d_in[0];
    const int*   ei     = (const int*)d_in[1];
    const int*   walks  = (const int*)d_in[2];
    const int*   negs   = (const int*)d_in[3];
    const float* W1     = (const float*)d_in[4];
    const float* a_src1 = (const float*)d_in[5];
    const float* a_dst1 = (const float*)d_in[6];
    const float* b1     = (const float*)d_in[7];
    const float* W2     = (const float*)d_in[8];
    const float* a_src2 = (const float*)d_in[9];
    const float* a_dst2 = (const float*)d_in[10];
    const float* b2     = (const float*)d_in[11];
    float* out = (float*)d_out;

    float* ws = (float*)d_ws;
    size_t off = 0;
    float* r_xw8   = ws + off; off += (size_t)(N_NODES + 1) * 64;  // [N+1][256] fp8 (sentinel row)
    float* r_emb1b = ws + off; off += (size_t)N_NODES * 128;       // [N][256] bf16
    float* r_embn8 = ws + off; off += (size_t)N_NODES * 128;       // [N][512] fp8
    float* r_xb    = ws + off; off += (size_t)N_NODES * 64;        // [N][128] bf16
    float* r_wt1   = ws + off; off += 256 * 64;                    // [256][128] bf16
    float* r_wt2   = ws + off; off += 256 * 128;                   // [256][256] bf16
    float* als1  = ws + off; off += (N_NODES + 1) * HEADS_1;       // sentinel row
    float* ald1  = ws + off; off += N_NODES * HEADS_1;
    float* als2  = ws + off; off += N_NODES + 1;                   // sentinel
    float* ald2  = ws + off; off += N_NODES;
    int* deg       = (int*)(ws + off); off += N_NODES;
    int* excl      = (int*)(ws + off); off += N_NODES;
    int* bsum      = (int*)(ws + off); off += 256;
    int* row_start = (int*)(ws + off); off += N_NODES + 1;
    int* cursor    = (int*)(ws + off); off += N_NODES;
    int* srclist   = (int*)(ws + off); off += E_PAD;
    uint*   xw8   = (uint*)r_xw8;
    ushort* emb1b = (ushort*)r_emb1b;
    uint*   embn8 = (uint*)r_embn8;
    ushort* xb    = (ushort*)r_xb;
    ushort* wt1   = (ushort*)r_wt1;
    ushort* wt2   = (ushort*)r_wt2;

    hipMemsetAsync(out, 0, sizeof(float) * out_size, stream);
    hipMemsetAsync(deg, 0, sizeof(int) * N_NODES, stream);
    hipMemsetAsync(cursor, 0, sizeof(int) * N_NODES, stream);

    // ---- CSR build (padded rows, sentinel-filled; shared by both layers) ----
    deg_kernel<<<(E_EDGES + 255) / 256, 256, 0, stream>>>(ei, deg);
    scan_a<<<SCAN_BLOCKS, 256, 0, stream>>>(deg, excl, bsum);
    scan_b<<<1, 256, 0, stream>>>(bsum);
    scan_c2<<<SCAN_BLOCKS, 256, 0, stream>>>(deg, excl, bsum, row_start);
    fill_sent_kernel<<<(E_PAD + 255) / 256, 256, 0, stream>>>(srclist, E_PAD);
    bucket_kernel<<<(E_EDGES + 255) / 256, 256, 0, stream>>>(ei, row_start, cursor, srclist);
    sent_al_kernel<<<1, 64, 0, stream>>>(als1, als2);

    // ---- bf16 conversions ----
    f32_to_bf16_kernel<<<(N_NODES * FDIM_IN / 4 + 255) / 256, 256, 0, stream>>>(
        x, (uint*)xb, N_NODES * FDIM_IN / 4);
    wtrans_kernel<<<(256 * 128 + 255) / 256, 256, 0, stream>>>(W1, wt1, 128);
    wtrans_kernel<<<(256 * 256 + 255) / 256, 256, 0, stream>>>(W2, wt2, 256);

    // ---- layer 1 (heads=8, hid=32), fused als/ald epilogue ----
    mfma_gemm<128, HEADS_1><<<N_NODES / 16, 256, 0, stream>>>(
        xb, wt1, xw8, a_src1, a_dst1, als1, ald1);
    gat_gather1<<<N_NODES / 4, 256, 0, stream>>>(
        row_start, srclist, als1, ald1, xw8, b1, emb1b);

    // ---- layer 2 (heads=1, hid=256), fused als/ald + normalize + fp8 pack ----
    mfma_gemm<256, 1><<<N_NODES / 16, 256, 0, stream>>>(
        emb1b, wt2, xw8, a_src2, a_dst2, als2, ald2);
    gat_gather2<<<N_NODES / 4, 256, 0, stream>>>(
        row_start, srclist, als2, ald2, xw8, b2, emb1b, embn8);

    // ---- contrastive loss (fp8 MFMA, one job per wave) ----
    loss_mfma_kernel<<<NUM_WALKS * 4, 768, 0, stream>>>(embn8, walks, negs, out);
}

// Round 15
// 381.281 us; speedup vs baseline: 1.1411x; 1.1411x over previous
//
#include <hip/hip_runtime.h>
#include <math.h>

#define N_NODES 50000
#define N_PAD 50048                     // 64-row padded
#define E_EDGES 800000
#define E_PAD (E_EDGES + 4 * N_NODES)   // padded srclist capacity (pad to x4)
#define FDIM_IN 128
#define HID_1 32
#define HEADS_1 8
#define H1DIM 256
#define NUM_WALKS 512
#define WALK_LEN 64
#define WINDOW 5
#define NEG_S 10
#define TEMP 0.07f
#define INV_TEMP (1.0f / 0.07f)
#define NEG_SLOPE 0.2f
#define LOG2E 1.44269504f

#define SCAN_BLOCKS ((N_NODES + 255) / 256)   // 196

typedef unsigned int uint;
typedef unsigned short ushort;
typedef long long i64_t;
typedef __attribute__((ext_vector_type(8))) short bf16x8;
typedef __attribute__((ext_vector_type(4))) float f32x4;
typedef __attribute__((ext_vector_type(2))) float vf2;

__device__ __forceinline__ float leaky(float v) {
    return fmaxf(v, v * NEG_SLOPE);
}

__device__ __forceinline__ float bfl(uint u) { return __uint_as_float(u << 16); }
__device__ __forceinline__ float bfh(uint u) { return __uint_as_float(u & 0xffff0000u); }

__device__ __forceinline__ ushort f2bf(float x) {
    uint u = __float_as_uint(x);
    u = u + 0x7fffu + ((u >> 16) & 1u);   // round-to-nearest-even
    return (ushort)(u >> 16);
}

// pack 4 f32 -> 4 fp8(e4m3) in one uint (HW converter; self-consistent with decode)
__device__ __forceinline__ uint pk4fp8(float a, float b, float c, float d) {
    int u = __builtin_amdgcn_cvt_pk_fp8_f32(a, b, 0, false);
    u = __builtin_amdgcn_cvt_pk_fp8_f32(c, d, u, true);
    return (uint)u;
}

// ---------------- CSR build (rows padded to multiples of 4 with sentinel) ----------------

__global__ void deg_kernel(const int* __restrict__ ei, int* __restrict__ deg) {
    int e = blockIdx.x * blockDim.x + threadIdx.x;
    if (e < E_EDGES) atomicAdd(&deg[ei[E_EDGES + e]], 1);
}

__global__ __launch_bounds__(256) void scan_a(const int* __restrict__ deg,
                                              int* __restrict__ excl,
                                              int* __restrict__ bsum) {
    __shared__ int s[256];
    int t = threadIdx.x;
    int i = blockIdx.x * 256 + t;
    int d = (i < N_NODES) ? deg[i] : 0;
    int v = (d + 3) & ~3;                // padded degree
    s[t] = v;
    __syncthreads();
    for (int off = 1; off < 256; off <<= 1) {
        int tmp = (t >= off) ? s[t - off] : 0;
        __syncthreads();
        s[t] += tmp;
        __syncthreads();
    }
    if (i < N_NODES) excl[i] = s[t] - v;
    if (t == 255) bsum[blockIdx.x] = s[255];
}

__global__ __launch_bounds__(256) void scan_b(int* __restrict__ bsum) {
    __shared__ int s[256];
    int t = threadIdx.x;
    int v = (t < SCAN_BLOCKS) ? bsum[t] : 0;
    s[t] = v;
    __syncthreads();
    for (int off = 1; off < 256; off <<= 1) {
        int tmp = (t >= off) ? s[t - off] : 0;
        __syncthreads();
        s[t] += tmp;
        __syncthreads();
    }
    if (t < SCAN_BLOCKS) bsum[t] = s[t] - v;   // exclusive
}

__global__ void scan_c2(const int* __restrict__ deg,
                        int* __restrict__ excl, const int* __restrict__ bsum,
                        int* __restrict__ row_start) {
    int i = blockIdx.x * blockDim.x + threadIdx.x;
    if (i < N_NODES) {
        int rs = excl[i] + bsum[i >> 8];
        row_start[i] = rs;
        if (i == N_NODES - 1) row_start[N_NODES] = rs + ((deg[i] + 3) & ~3);
    }
}

__global__ void fill_sent_kernel(int* __restrict__ p, int n) {
    int i = blockIdx.x * blockDim.x + threadIdx.x;
    if (i < n) p[i] = N_NODES;           // sentinel node id
}

__global__ void sent_al_kernel(float* __restrict__ als1, float* __restrict__ als2) {
    int t = threadIdx.x;
    if (t < HEADS_1) als1[N_NODES * HEADS_1 + t] = -1e30f;
    if (t == HEADS_1) als2[N_NODES] = -1e30f;
}

__global__ void bucket_kernel(const int* __restrict__ ei,
                              const int* __restrict__ row_start,
                              int* __restrict__ cursor,
                              int* __restrict__ srclist) {
    int e = blockIdx.x * blockDim.x + threadIdx.x;
    if (e >= E_EDGES) return;
    int dst = ei[E_EDGES + e];
    int pos = atomicAdd(&cursor[dst], 1);
    srclist[row_start[dst] + pos] = ei[e];
}

// ---------------- dtype conversion ----------------

__global__ void f32_to_bf16_kernel(const float* __restrict__ src, uint* __restrict__ dst, int n4) {
    int i = blockIdx.x * blockDim.x + threadIdx.x;
    if (i >= n4) return;
    float4 v = ((const float4*)src)[i];
    uint2 p;
    p.x = (uint)f2bf(v.x) | ((uint)f2bf(v.y) << 16);
    p.y = (uint)f2bf(v.z) | ((uint)f2bf(v.w) << 16);
    ((uint2*)dst)[i] = p;
}

// W[K][256] fp32 -> Wt[256][K] bf16
__global__ void wtrans_kernel(const float* __restrict__ W, ushort* __restrict__ Wt, int K) {
    int tid = blockIdx.x * blockDim.x + threadIdx.x;
    if (tid >= 256 * K) return;
    int k = tid >> 8, n = tid & 255;
    Wt[n * K + k] = f2bf(W[k * 256 + n]);
}

// ---- MFMA GEMM, 64-row blocks: Y8[M][256] (fp8) = A[M][K] * W[K][256], bf16 in ----
// 4 waves; wave w owns cols 64w..64w+63; 4x4 accs of 16x16. Single barrier; fp8 pack
// via per-wave-private LDS transpose reusing the (dead) A-tile memory.
template<int K>
__global__ __launch_bounds__(256) void mfma_gemm64(
        const ushort* __restrict__ A,    // [Mpad][K] bf16
        const ushort* __restrict__ Wt,   // [256][K] bf16 (transposed)
        uint* __restrict__ Y8) {         // [M][256] fp8, 64 uints/row
    constexpr int KP = K + 8;
    constexpr int K8 = K / 8;
    __shared__ __align__(16) ushort As[64 * KP];   // K=128:17.4KB, K=256:33.8KB
    const int m0 = blockIdx.x * 64;
    const int t = threadIdx.x;
    const uint4* Ag = (const uint4*)(A + (size_t)m0 * K);
    uint4* As4 = (uint4*)As;
    for (int i = t; i < 64 * K8; i += 256) {
        int r = i / K8, c8 = i % K8;
        As4[r * (K8 + 1) + c8] = Ag[i];
    }
    __syncthreads();
    const int wv = __builtin_amdgcn_readfirstlane(t >> 6);
    const int lane = t & 63;
    const int n0 = wv * 64;
    const int mrow = lane & 15, q = lane >> 4;
    f32x4 acc[4][4];
#pragma unroll
    for (int mt = 0; mt < 4; mt++)
#pragma unroll
        for (int i = 0; i < 4; i++) acc[mt][i] = (f32x4){0.f, 0.f, 0.f, 0.f};
#pragma unroll
    for (int k0 = 0; k0 < K; k0 += 32) {
        bf16x8 a[4], b[4];
#pragma unroll
        for (int mt = 0; mt < 4; mt++)
            a[mt] = *(const bf16x8*)(As + (mt * 16 + mrow) * KP + k0 + q * 8);
#pragma unroll
        for (int i = 0; i < 4; i++)
            b[i] = *(const bf16x8*)(Wt + (uint)(n0 + i * 16 + mrow) * K + k0 + q * 8);
#pragma unroll
        for (int mt = 0; mt < 4; mt++)
#pragma unroll
            for (int i = 0; i < 4; i++)
                acc[mt][i] = __builtin_amdgcn_mfma_f32_16x16x32_bf16(a[mt], b[i], acc[mt][i], 0, 0, 0);
    }
    __syncthreads();                     // A-tile dead; reuse as per-wave scratch
    float* S = (float*)As + wv * 16 * 68;   // 16 rows x 68 floats, wave-private
    const int prow = lane >> 2, pj = lane & 3;   // pack: lane -> (row-in-tile, uint4 j)
#pragma unroll
    for (int mt = 0; mt < 4; mt++) {
#pragma unroll
        for (int i = 0; i < 4; i++)
#pragma unroll
            for (int r = 0; r < 4; r++)
                S[(q * 4 + r) * 68 + i * 16 + mrow] = acc[mt][i][r];
        // wave-internal LDS ordering: no barrier needed
        const float* cp = S + prow * 68 + pj * 16;
        uint4 o;
        o.x = pk4fp8(cp[0],  cp[1],  cp[2],  cp[3]);
        o.y = pk4fp8(cp[4],  cp[5],  cp[6],  cp[7]);
        o.z = pk4fp8(cp[8],  cp[9],  cp[10], cp[11]);
        o.w = pk4fp8(cp[12], cp[13], cp[14], cp[15]);
        const int row = m0 + mt * 16 + prow;
        if (row < N_NODES)
            ((uint4*)(Y8 + (size_t)row * 64))[wv * 4 + pj] = o;
    }
}

// ---------------- attention logits (scaled by log2e for exp2 in gathers) ----------------

template<int H>
__global__ __launch_bounds__(256) void al_wave_kernel(
        const uint* __restrict__ xw8,                    // fp8 rows, 64 uints/row
        const float* __restrict__ a_src, const float* __restrict__ a_dst,
        float* __restrict__ als, float* __restrict__ ald) {
    int wid = (blockIdx.x * 256 + threadIdx.x) >> 6;
    int lane = threadIdx.x & 63;
    if (wid >= N_NODES) return;
    uint u = xw8[((uint)wid << 6) + lane];
    vf2 lo = __builtin_amdgcn_cvt_pk_f32_fp8((int)u, false);
    vf2 hi = __builtin_amdgcn_cvt_pk_f32_fp8((int)u, true);
    int col = lane * 4;
    float s = lo[0] * a_src[col] + lo[1] * a_src[col + 1] + hi[0] * a_src[col + 2] + hi[1] * a_src[col + 3];
    float d = lo[0] * a_dst[col] + lo[1] * a_dst[col + 1] + hi[0] * a_dst[col + 2] + hi[1] * a_dst[col + 3];
#pragma unroll
    for (int o = 32 / H; o > 0; o >>= 1) {
        s += __shfl_xor(s, o, 64);
        d += __shfl_xor(d, o, 64);
    }
    if ((lane & (64 / H - 1)) == 0) {
        int h = lane / (64 / H);
        als[wid * H + h] = s * LOG2E;
        ald[wid * H + h] = d * LOG2E;
    }
}

#define UN 4

// layer-1 gather: scalar wid, padded rows (no clamps), exp2 logits, 32-bit offsets
__global__ __launch_bounds__(256) void gat_gather1(
        const int* __restrict__ row_start, const int* __restrict__ srclist,
        const float* __restrict__ als, const float* __restrict__ ald,
        const uint* __restrict__ xw8,                    // fp8 rows, 64 uints/row
        const float* __restrict__ bias,
        ushort* __restrict__ emb1b) {                    // [N][256] bf16
    const int wid = __builtin_amdgcn_readfirstlane(blockIdx.x * 4 + (threadIdx.x >> 6));
    const uint lane = threadIdx.x & 63;
    const uint h = lane >> 3;
    const float ald_n = ald[wid * HEADS_1 + h];
    const int beg = row_start[wid], end = row_start[wid + 1];

    float ex0 = __builtin_amdgcn_exp2f(leaky(als[wid * HEADS_1 + h] + ald_n));
    uint u = xw8[((uint)wid << 6) + lane];
    vf2 lo = __builtin_amdgcn_cvt_pk_f32_fp8((int)u, false);
    vf2 hi = __builtin_amdgcn_cvt_pk_f32_fp8((int)u, true);
    float den = ex0;
    float a0 = ex0 * lo[0], a1 = ex0 * lo[1];
    float a2 = ex0 * hi[0], a3 = ex0 * hi[1];

    for (int i = beg; i < end; i += UN) {
        uint ss[UN]; uint rr[UN]; float ee[UN];
#pragma unroll
        for (int j = 0; j < UN; j++) ss[j] = (uint)srclist[i + j];
#pragma unroll
        for (int j = 0; j < UN; j++) rr[j] = xw8[(ss[j] << 6) + lane];
#pragma unroll
        for (int j = 0; j < UN; j++) ee[j] = als[ss[j] * HEADS_1 + h];
#pragma unroll
        for (int j = 0; j < UN; j++) {
            float ex = __builtin_amdgcn_exp2f(leaky(ee[j] + ald_n));   // sentinel -> 0
            vf2 l2 = __builtin_amdgcn_cvt_pk_f32_fp8((int)rr[j], false);
            vf2 h2 = __builtin_amdgcn_cvt_pk_f32_fp8((int)rr[j], true);
            den += ex;
            a0 += ex * l2[0]; a1 += ex * l2[1];
            a2 += ex * h2[0]; a3 += ex * h2[1];
        }
    }
    float inv = 1.f / den;
    float4 bv = ((const float4*)bias)[lane];
    float4 r;
    r.x = a0 * inv + bv.x; r.y = a1 * inv + bv.y;
    r.z = a2 * inv + bv.z; r.w = a3 * inv + bv.w;
    r.x = r.x > 0.f ? r.x : __expf(r.x) - 1.f;
    r.y = r.y > 0.f ? r.y : __expf(r.y) - 1.f;
    r.z = r.z > 0.f ? r.z : __expf(r.z) - 1.f;
    r.w = r.w > 0.f ? r.w : __expf(r.w) - 1.f;
    uint2 p;
    p.x = (uint)f2bf(r.x) | ((uint)f2bf(r.y) << 16);
    p.y = (uint)f2bf(r.z) | ((uint)f2bf(r.w) << 16);
    ((uint2*)emb1b)[((uint)wid << 6) + lane] = p;
}

// layer-2 gather fused with normalize + fp8 pack of embn
__global__ __launch_bounds__(256) void gat_gather2(
        const int* __restrict__ row_start, const int* __restrict__ srclist,
        const float* __restrict__ als, const float* __restrict__ ald,
        const uint* __restrict__ xw8,                    // fp8 rows, 64 uints/row
        const float* __restrict__ bias,
        const ushort* __restrict__ emb1b,                // [N][256] bf16
        uint* __restrict__ embn8) {                      // [N][512] fp8, 128 uints/row
    const int wid = __builtin_amdgcn_readfirstlane(blockIdx.x * 4 + (threadIdx.x >> 6));
    const uint lane = threadIdx.x & 63;
    const float ald_n = ald[wid];
    const int beg = row_start[wid], end = row_start[wid + 1];

    float ex0 = __builtin_amdgcn_exp2f(leaky(als[wid] + ald_n));
    uint u = xw8[((uint)wid << 6) + lane];
    vf2 lo = __builtin_amdgcn_cvt_pk_f32_fp8((int)u, false);
    vf2 hi = __builtin_amdgcn_cvt_pk_f32_fp8((int)u, true);
    float den = ex0;
    float a0 = ex0 * lo[0], a1 = ex0 * lo[1];
    float a2 = ex0 * hi[0], a3 = ex0 * hi[1];

    for (int i = beg; i < end; i += UN) {
        uint ss[UN]; uint rr[UN]; float ee[UN];
#pragma unroll
        for (int j = 0; j < UN; j++) ss[j] = (uint)srclist[i + j];
#pragma unroll
        for (int j = 0; j < UN; j++) rr[j] = xw8[(ss[j] << 6) + lane];
#pragma unroll
        for (int j = 0; j < UN; j++) ee[j] = als[ss[j]];
#pragma unroll
        for (int j = 0; j < UN; j++) {
            float ex = __builtin_amdgcn_exp2f(leaky(ee[j] + ald_n));   // sentinel -> 0
            vf2 l2 = __builtin_amdgcn_cvt_pk_f32_fp8((int)rr[j], false);
            vf2 h2 = __builtin_amdgcn_cvt_pk_f32_fp8((int)rr[j], true);
            den += ex;
            a0 += ex * l2[0]; a1 += ex * l2[1];
            a2 += ex * h2[0]; a3 += ex * h2[1];
        }
    }
    float inv = 1.f / den;
    float4 bv = ((const float4*)bias)[lane];
    float4 e2;
    e2.x = a0 * inv + bv.x; e2.y = a1 * inv + bv.y;
    e2.z = a2 * inv + bv.z; e2.w = a3 * inv + bv.w;
    uint2 u1 = ((const uint2*)emb1b)[((uint)wid << 6) + lane];
    float4 e1;
    e1.x = bfl(u1.x); e1.y = bfh(u1.x); e1.z = bfl(u1.y); e1.w = bfh(u1.y);

    float ssum = e1.x * e1.x + e1.y * e1.y + e1.z * e1.z + e1.w * e1.w
               + e2.x * e2.x + e2.y * e2.y + e2.z * e2.z + e2.w * e2.w;
#pragma unroll
    for (int o = 32; o > 0; o >>= 1) ssum += __shfl_xor(ssum, o, 64);
    float innv = 1.f / fmaxf(sqrtf(ssum), 1e-8f);

    uint p1 = pk4fp8(e1.x * innv, e1.y * innv, e1.z * innv, e1.w * innv);
    uint p2 = pk4fp8(e2.x * innv, e2.y * innv, e2.z * innv, e2.w * innv);
    embn8[((uint)wid << 7) + lane] = p1;        // dims 0..255   (emb1 part)
    embn8[((uint)wid << 7) + 64 + lane] = p2;   // dims 256..511 (emb2 part)
}

// ---------------- MFMA contrastive loss (fp8) ----------------

#define ANCH 16                         // anchors per block (walk segment)
#define MAXROWS (ANCH + 2 * WINDOW)     // 26 LDS rows max
#define ROWU 130                        // 520 B row stride (2 banks mod 32, conflict-free)

// one block per 16-anchor segment, 768 threads = 12 waves, one tile-job per wave.
__global__ __launch_bounds__(768) void loss_mfma_kernel(
        const uint* __restrict__ embn8,    // [N][512] fp8, 128 uints/row
        const int* __restrict__ walks, const int* __restrict__ negs,
        float* __restrict__ out) {
    __shared__ __align__(16) uint srows8[MAXROWS * ROWU];   // 13.5 KB
    __shared__ int wids[MAXROWS];
    __shared__ int snid[160];
    __shared__ float possum[16];
    __shared__ float negsum[16];
    const int blk = blockIdx.x;
    const int b = blk >> 2;                  // walk
    const int l0 = (blk & 3) * ANCH;         // first anchor of segment
    const int base = (l0 - WINDOW) > 0 ? (l0 - WINDOW) : 0;
    const int hi = (l0 + ANCH - 1 + WINDOW) < (WALK_LEN - 1) ? (l0 + ANCH - 1 + WINDOW) : (WALK_LEN - 1);
    const int cnt = hi - base + 1;           // 21..26
    const int t = threadIdx.x;
    const int w = __builtin_amdgcn_readfirstlane(t >> 6);   // 0..11 = this wave's job
    const int lane = t & 63;
    if (t < cnt) wids[t] = walks[b * WALK_LEN + base + t];
    if (t >= 64 && t < 64 + 160) snid[t - 64] = negs[(b * WALK_LEN + l0) * NEG_S + (t - 64)];
    if (t >= 224 && t < 240) { possum[t - 224] = 0.f; negsum[t - 224] = 0.f; }
    __syncthreads();
    for (int r = w; r < cnt; r += 12)
        ((uint2*)(srows8 + r * ROWU))[lane] = ((const uint2*)(embn8 + ((uint)wids[r] << 7)))[lane];
    __syncthreads();

    const int mrow = lane & 15, q = lane >> 4;
    const int arow = (l0 - base) + mrow;     // LDS row of anchor #mrow
    const char* embc = (const char*)embn8;   // byte rows, stride 512
    const char* ap = (const char*)(srows8 + arow * ROWU) + q * 8;

    const int job = w;
    f32x4 acc0 = {0.f, 0.f, 0.f, 0.f};
    f32x4 acc1 = {0.f, 0.f, 0.f, 0.f};
    if (job < 10) {
        // ---- neg tile: cands c = 16*job .. +15, col = mrow ----
        const int c = job * 16 + mrow;
        const int node = snid[c];
        const char* bp = embc + (((uint)node << 9) + (uint)(q * 8));
#pragma unroll
        for (int k0 = 0; k0 < 256; k0 += 32) {
            i64_t a0 = *(const i64_t*)(ap + k0);
            i64_t b0 = *(const i64_t*)(bp + k0);
            acc0 = __builtin_amdgcn_mfma_f32_16x16x32_fp8_fp8(a0, b0, acc0, 0, 0, 0);
            i64_t a1 = *(const i64_t*)(ap + k0 + 256);
            i64_t b1 = *(const i64_t*)(bp + k0 + 256);
            acc1 = __builtin_amdgcn_mfma_f32_16x16x32_fp8_fp8(a1, b1, acc1, 0, 0, 0);
        }
        const int owner = c / 10;
#pragma unroll
        for (int reg = 0; reg < 4; reg++) {
            const int a_local = q * 4 + reg;
            float e = 0.f;
            if (owner == a_local) {
                const int l_a = l0 + a_local;
                bool msk = false;
#pragma unroll
                for (int dj = -WINDOW; dj <= WINDOW; dj++) {
                    if (dj == 0) continue;
                    int p = l_a + dj;
                    if (p >= 0 && p < WALK_LEN && wids[p - base] == node) msk = true;
                }
                if (!msk) e = __expf((acc0[reg] + acc1[reg]) * INV_TEMP);
            }
#pragma unroll
            for (int o = 1; o < 16; o <<= 1) e += __shfl_xor(e, o, 64);
            if (mrow == 0 && e != 0.f) atomicAdd(&negsum[a_local], e);
        }
    } else {
        // ---- pos tile: LDS rows r = 16*(job-10) .. +15 ----
        const int r = (job - 10) * 16 + mrow;
        const int rc = r < (cnt - 1) ? r : (cnt - 1);
        const char* bp = (const char*)(srows8 + rc * ROWU) + q * 8;
#pragma unroll
        for (int k0 = 0; k0 < 256; k0 += 32) {
            i64_t a0 = *(const i64_t*)(ap + k0);
            i64_t b0 = *(const i64_t*)(bp + k0);
            acc0 = __builtin_amdgcn_mfma_f32_16x16x32_fp8_fp8(a0, b0, acc0, 0, 0, 0);
            i64_t a1 = *(const i64_t*)(ap + k0 + 256);
            i64_t b1 = *(const i64_t*)(bp + k0 + 256);
            acc1 = __builtin_amdgcn_mfma_f32_16x16x32_fp8_fp8(a1, b1, acc1, 0, 0, 0);
        }
        const int pg = base + r;                 // walk position of this row
#pragma unroll
        for (int reg = 0; reg < 4; reg++) {
            const int a_local = q * 4 + reg;
            const int l_a = l0 + a_local;
            const int d = pg - l_a;
            bool use = (r < cnt) && (d != 0) && (d >= -WINDOW) && (d <= WINDOW);
            float e = use ? __expf((acc0[reg] + acc1[reg]) * INV_TEMP) : 0.f;
#pragma unroll
            for (int o = 1; o < 16; o <<= 1) e += __shfl_xor(e, o, 64);
            if (mrow == 0 && e != 0.f) atomicAdd(&possum[a_local], e);
        }
    }
    __syncthreads();
    if (t < 16) {
        float term = logf(1.f + negsum[t] / possum[t]);   // possum > 0 always
#pragma unroll
        for (int o = 8; o > 0; o >>= 1) term += __shfl_xor(term, o, 64);
        if (t == 0) atomicAdd(out, term);
    }
}

extern "C" void kernel_launch(void* const* d_in, const int* in_sizes, int n_in,
                              void* d_out, int out_size, void* d_ws, size_t ws_size,
                              hipStream_t stream) {
    const float* x      = (const float*)d_in[0];
    const int*   ei     = (const int*)d_in[1];
    const int*   walks  = (const int*)d_in[2];
    const int*   negs   = (const int*)d_in[3];
    const float* W1     = (const float*)d_in[4];
    const float* a_src1 = (const float*)d_in[5];
    const float* a_dst1 = (const float*)d_in[6];
    const float* b1     = (const float*)d_in[7];
    const float* W2     = (const float*)d_in[8];
    const float* a_src2 = (const float*)d_in[9];
    const float* a_dst2 = (const float*)d_in[10];
    const float* b2     = (const float*)d_in[11];
    float* out = (float*)d_out;

    float* ws = (float*)d_ws;
    size_t off = 0;
    float* r_xw8   = ws + off; off += (size_t)(N_NODES + 1) * 64;  // [N+1][256] fp8 (sentinel row)
    float* r_emb1b = ws + off; off += (size_t)N_PAD * 128;         // [Npad][256] bf16
    float* r_embn8 = ws + off; off += (size_t)N_NODES * 128;       // [N][512] fp8
    float* r_xb    = ws + off; off += (size_t)N_PAD * 64;          // [Npad][128] bf16
    float* r_wt1   = ws + off; off += 256 * 64;                    // [256][128] bf16
    float* r_wt2   = ws + off; off += 256 * 128;                   // [256][256] bf16
    float* als1  = ws + off; off += (N_NODES + 1) * HEADS_1;       // sentinel row
    float* ald1  = ws + off; off += N_NODES * HEADS_1;
    float* als2  = ws + off; off += N_NODES + 1;                   // sentinel
    float* ald2  = ws + off; off += N_NODES;
    int* deg       = (int*)(ws + off); off += N_NODES;
    int* excl      = (int*)(ws + off); off += N_NODES;
    int* bsum      = (int*)(ws + off); off += 256;
    int* row_start = (int*)(ws + off); off += N_NODES + 1;
    int* cursor    = (int*)(ws + off); off += N_NODES;
    int* srclist   = (int*)(ws + off); off += E_PAD;
    uint*   xw8   = (uint*)r_xw8;
    ushort* emb1b = (ushort*)r_emb1b;
    uint*   embn8 = (uint*)r_embn8;
    ushort* xb    = (ushort*)r_xb;
    ushort* wt1   = (ushort*)r_wt1;
    ushort* wt2   = (ushort*)r_wt2;

    hipMemsetAsync(out, 0, sizeof(float) * out_size, stream);
    hipMemsetAsync(deg, 0, sizeof(int) * N_NODES, stream);
    hipMemsetAsync(cursor, 0, sizeof(int) * N_NODES, stream);

    // ---- CSR build (padded rows, sentinel-filled; shared by both layers) ----
    deg_kernel<<<(E_EDGES + 255) / 256, 256, 0, stream>>>(ei, deg);
    scan_a<<<SCAN_BLOCKS, 256, 0, stream>>>(deg, excl, bsum);
    scan_b<<<1, 256, 0, stream>>>(bsum);
    scan_c2<<<SCAN_BLOCKS, 256, 0, stream>>>(deg, excl, bsum, row_start);
    fill_sent_kernel<<<(E_PAD + 255) / 256, 256, 0, stream>>>(srclist, E_PAD);
    bucket_kernel<<<(E_EDGES + 255) / 256, 256, 0, stream>>>(ei, row_start, cursor, srclist);
    sent_al_kernel<<<1, 64, 0, stream>>>(als1, als2);

    // ---- bf16 conversions ----
    f32_to_bf16_kernel<<<(N_NODES * FDIM_IN / 4 + 255) / 256, 256, 0, stream>>>(
        x, (uint*)xb, N_NODES * FDIM_IN / 4);
    wtrans_kernel<<<(256 * 128 + 255) / 256, 256, 0, stream>>>(W1, wt1, 128);
    wtrans_kernel<<<(256 * 256 + 255) / 256, 256, 0, stream>>>(W2, wt2, 256);

    // ---- layer 1 (heads=8, hid=32) ----
    mfma_gemm64<128><<<N_PAD / 64, 256, 0, stream>>>(xb, wt1, xw8);
    al_wave_kernel<HEADS_1><<<(N_NODES * 64 + 255) / 256, 256, 0, stream>>>(
        xw8, a_src1, a_dst1, als1, ald1);
    gat_gather1<<<N_NODES / 4, 256, 0, stream>>>(
        row_start, srclist, als1, ald1, xw8, b1, emb1b);

    // ---- layer 2 (heads=1, hid=256), fused normalize + fp8 pack ----
    mfma_gemm64<256><<<N_PAD / 64, 256, 0, stream>>>(emb1b, wt2, xw8);
    al_wave_kernel<1><<<(N_NODES * 64 + 255) / 256, 256, 0, stream>>>(
        xw8, a_src2, a_dst2, als2, ald2);
    gat_gather2<<<N_NODES / 4, 256, 0, stream>>>(
        row_start, srclist, als2, ald2, xw8, b2, emb1b, embn8);

    // ---- contrastive loss (fp8 MFMA, one job per wave) ----
    loss_mfma_kernel<<<NUM_WALKS * 4, 768, 0, stream>>>(embn8, walks, negs, out);
}